// Round 10
// baseline (326.196 us; speedup 1.0000x reference)
//
#include <hip/hip_runtime.h>
#include <math.h>

#define LSEQ 2048
#define HCH  512
#define NST  64
#define NBATCH 8
#define PIf 3.14159265358979f

// Padded LDS layout: phys(i) = i + i/8 (verified r2)
#define PHYS(i) ((i) + ((i) >> 3))
#define LDSN 2304            // 2048-pt FFT buffers (kf kernel)
#define LDSN4 4608           // 4096-pt FFT buffer (conv kernel): 36864 B

__device__ __forceinline__ float2 cmul(float2 a, float2 b) {
    return make_float2(a.x * b.x - a.y * b.y, a.x * b.y + a.y * b.x);
}
__device__ __forceinline__ float2 cadd(float2 a, float2 b) { return make_float2(a.x + b.x, a.y + b.y); }
__device__ __forceinline__ float2 csub(float2 a, float2 b) { return make_float2(a.x - b.x, a.y - b.y); }
__device__ __forceinline__ float2 csq(float2 a) { return make_float2(a.x * a.x - a.y * a.y, 2.f * a.x * a.y); }
template<int INV>
__device__ __forceinline__ float2 rot90(float2 a) {
    return INV ? make_float2(-a.y, a.x) : make_float2(a.y, -a.x);
}

// ---------------------------------------------------------------------------
// Radix-8 Stockham pass, ping-pong, N=2048/NT=256 (VERBATIM r2; kf kernel).
// ---------------------------------------------------------------------------
template<int INV, int STAGE>
__device__ __forceinline__ void radix8_pass(const float2* __restrict__ src,
                                            float2* __restrict__ dst, int tid)
{
    const int Ns  = 1 << STAGE;
    const int lam = tid & (Ns - 1);
    const int G   = ((tid >> STAGE) << (STAGE + 3)) + lam;

    float2 x0 = src[PHYS(tid)];
    float2 x1 = src[PHYS(tid + 256)];
    float2 x2 = src[PHYS(tid + 512)];
    float2 x3 = src[PHYS(tid + 768)];
    float2 x4 = src[PHYS(tid + 1024)];
    float2 x5 = src[PHYS(tid + 1280)];
    float2 x6 = src[PHYS(tid + 1536)];
    float2 x7 = src[PHYS(tid + 1792)];

    const float SGN = INV ? 1.f : -1.f;
    float sn, cs;
    __sincosf(SGN * (PIf / (float)(4 * Ns)) * (float)lam, &sn, &cs);
    const float2 T3 = make_float2(cs, sn);
    const float2 T2 = csq(T3);
    const float2 T1 = csq(T2);
    const float r2 = 0.70710678118f;
    const float2 U = cmul(T3, make_float2(r2, SGN * r2));

    float2 t;
    t = cmul(T1, x4); float2 a0 = cadd(x0, t), a4 = csub(x0, t);
    t = cmul(T1, x5); float2 a1 = cadd(x1, t), a5 = csub(x1, t);
    t = cmul(T1, x6); float2 a2 = cadd(x2, t), a6 = csub(x2, t);
    t = cmul(T1, x7); float2 a3 = cadd(x3, t), a7 = csub(x3, t);
    t = cmul(T2, a2);             float2 b0 = cadd(a0, t), b2 = csub(a0, t);
    t = cmul(T2, a3);             float2 b1 = cadd(a1, t), b3 = csub(a1, t);
    t = rot90<INV>(cmul(T2, a6)); float2 b4 = cadd(a4, t), b6 = csub(a4, t);
    t = rot90<INV>(cmul(T2, a7)); float2 b5 = cadd(a5, t), b7 = csub(a5, t);
    t = cmul(T3, b1);             dst[PHYS(G)]          = cadd(b0, t); dst[PHYS(G + 4 * Ns)] = csub(b0, t);
    t = rot90<INV>(cmul(T3, b3)); dst[PHYS(G + 2 * Ns)] = cadd(b2, t); dst[PHYS(G + 6 * Ns)] = csub(b2, t);
    t = cmul(U, b5);              dst[PHYS(G + Ns)]     = cadd(b4, t); dst[PHYS(G + 5 * Ns)] = csub(b4, t);
    t = rot90<INV>(cmul(U, b7));  dst[PHYS(G + 3 * Ns)] = cadd(b6, t); dst[PHYS(G + 7 * Ns)] = csub(b6, t);
}

template<int INV>
__device__ float2* fft2048(float2* bufA, float2* bufB)
{
    const int tid = threadIdx.x;
    __syncthreads();
    radix8_pass<INV, 0>(bufA, bufB, tid);
    __syncthreads();
    radix8_pass<INV, 3>(bufB, bufA, tid);
    __syncthreads();
    radix8_pass<INV, 6>(bufA, bufB, tid);
    __syncthreads();
    const float SGN = INV ? 1.f : -1.f;
#pragma unroll
    for (int q = 0; q < 2; ++q) {
        const int j = tid + (q << 8);
        float2 A  = bufB[PHYS(j)];
        float2 C  = bufB[PHYS(j + 512)];
        float2 B  = bufB[PHYS(j + 1024)];
        float2 Dd = bufB[PHYS(j + 1536)];
        float sn, cs;
        __sincosf(SGN * (PIf / 1024.f) * (float)j, &sn, &cs);
        const float2 v = make_float2(cs, sn);
        const float2 w = csq(v);
        float2 t = cmul(w, B);  float2 m1 = cadd(A, t), m2 = csub(A, t);
        t = cmul(w, Dd);        float2 m3 = cadd(C, t), m4 = csub(C, t);
        const float2 t3 = cmul(v, m3);
        const float2 t4 = rot90<INV>(cmul(v, m4));
        bufA[PHYS(j)]        = cadd(m1, t3);
        bufA[PHYS(j + 1024)] = csub(m1, t3);
        bufA[PHYS(j + 512)]  = cadd(m2, t4);
        bufA[PHYS(j + 1536)] = csub(m2, t4);
    }
    __syncthreads();
    return bufA;
}

// ---------------------------------------------------------------------------
// Radix-8 in-place pass, N=4096/NT=512 (same verified stage template:
// stage twiddles are N-independent; only the read stride (NT) changes).
// ---------------------------------------------------------------------------
template<int INV, int STAGE>
__device__ __forceinline__ void radix8_ip4096(float2* __restrict__ buf, int tid)
{
    __syncthreads();
    float2 x0 = buf[PHYS(tid)];
    float2 x1 = buf[PHYS(tid + 512)];
    float2 x2 = buf[PHYS(tid + 1024)];
    float2 x3 = buf[PHYS(tid + 1536)];
    float2 x4 = buf[PHYS(tid + 2048)];
    float2 x5 = buf[PHYS(tid + 2560)];
    float2 x6 = buf[PHYS(tid + 3072)];
    float2 x7 = buf[PHYS(tid + 3584)];
    __syncthreads();

    const int Ns  = 1 << STAGE;
    const int lam = tid & (Ns - 1);
    const int G   = ((tid >> STAGE) << (STAGE + 3)) + lam;
    const float SGN = INV ? 1.f : -1.f;
    float sn, cs;
    __sincosf(SGN * (PIf / (float)(4 * Ns)) * (float)lam, &sn, &cs);
    const float2 T3 = make_float2(cs, sn);
    const float2 T2 = csq(T3);
    const float2 T1 = csq(T2);
    const float r2 = 0.70710678118f;
    const float2 U = cmul(T3, make_float2(r2, SGN * r2));
    float2 t;
    t = cmul(T1, x4); float2 a0 = cadd(x0, t), a4 = csub(x0, t);
    t = cmul(T1, x5); float2 a1 = cadd(x1, t), a5 = csub(x1, t);
    t = cmul(T1, x6); float2 a2 = cadd(x2, t), a6 = csub(x2, t);
    t = cmul(T1, x7); float2 a3 = cadd(x3, t), a7 = csub(x3, t);
    t = cmul(T2, a2);             float2 b0 = cadd(a0, t), b2 = csub(a0, t);
    t = cmul(T2, a3);             float2 b1 = cadd(a1, t), b3 = csub(a1, t);
    t = rot90<INV>(cmul(T2, a6)); float2 b4 = cadd(a4, t), b6 = csub(a4, t);
    t = rot90<INV>(cmul(T2, a7)); float2 b5 = cadd(a5, t), b7 = csub(a5, t);
    t = cmul(T3, b1);             buf[PHYS(G)]          = cadd(b0, t); buf[PHYS(G + 4 * Ns)] = csub(b0, t);
    t = rot90<INV>(cmul(T3, b3)); buf[PHYS(G + 2 * Ns)] = cadd(b2, t); buf[PHYS(G + 6 * Ns)] = csub(b2, t);
    t = cmul(U, b5);              buf[PHYS(G + Ns)]     = cadd(b4, t); buf[PHYS(G + 5 * Ns)] = csub(b4, t);
    t = rot90<INV>(cmul(U, b7));  buf[PHYS(G + 3 * Ns)] = cadd(b6, t); buf[PHYS(G + 7 * Ns)] = csub(b6, t);
}

// ---------------------------------------------------------------------------
// Cauchy (VERBATIM r7).
// ---------------------------------------------------------------------------
__global__ __launch_bounds__(256, 4)
void s4_cauchy_kernel(const float* __restrict__ Lr, const float* __restrict__ Li,
                      const float* __restrict__ Pr, const float* __restrict__ Pi,
                      const float* __restrict__ Br, const float* __restrict__ Bi,
                      const float* __restrict__ Cr, const float* __restrict__ Ci,
                      const float* __restrict__ log_dt, float2* __restrict__ at_out)
{
    __shared__ float4 F0[NST];
    __shared__ float4 F1[NST];
    __shared__ float  q1s[NST];

    const int h    = blockIdx.x >> 1;
    const int half = blockIdx.x & 1;
    const int tid  = threadIdx.x;

    if (tid < NST) {
        const float pr = Pr[tid], pi = Pi[tid], br = Br[tid], bi = Bi[tid];
        const float cr = Cr[h * NST + tid], ci = Ci[h * NST + tid];
        F0[tid]  = make_float4(Lr[tid], Li[tid], cr * br + ci * bi, cr * bi - ci * br);
        F1[tid]  = make_float4(cr * pr + ci * pi, cr * pi - ci * pr,
                               pr * br + pi * bi, pr * bi - pi * br);
        q1s[tid] = pr * pr + pi * pi;
    }
    __syncthreads();

    const float dt = expf(log_dt[h]);
    const float a  = 2.0f / dt;

    float tt[4], g[4];
#pragma unroll
    for (int p = 0; p < 4; ++p) {
        const int l = (half << 10) + (p << 8) + tid;
        tt[p] = tanf(PIf * (float)l * (1.0f / 2048.0f));
        g[p]  = a * tt[p];
    }

    float k00r[4], k00i[4], k01r[4], k01i[4];
    float k10r[4], k10i[4], k11r[4], k11i[4];
#pragma unroll
    for (int p = 0; p < 4; ++p) {
        k00r[p] = 0.f; k00i[p] = 0.f; k01r[p] = 0.f; k01i[p] = 0.f;
        k10r[p] = 0.f; k10i[p] = 0.f; k11r[p] = 0.f; k11i[p] = 0.f;
    }

#pragma unroll 2
    for (int n = 0; n < NST; ++n) {
        const float4 f0 = F0[n];
        const float4 f1 = F1[n];
        const float q1 = q1s[n];
        const float x  = -f0.x;
        const float x2 = x * x;
#pragma unroll
        for (int p = 0; p < 4; ++p) {
            const float y   = g[p] - f0.y;
            const float inv = __builtin_amdgcn_rcpf(fmaf(y, y, x2));
            const float rr  = x * inv;
            const float ri  = -y * inv;
            k00r[p] = fmaf(f0.z, rr, fmaf(-f0.w, ri, k00r[p]));
            k00i[p] = fmaf(f0.z, ri, fmaf( f0.w, rr, k00i[p]));
            k01r[p] = fmaf(f1.x, rr, fmaf(-f1.y, ri, k01r[p]));
            k01i[p] = fmaf(f1.x, ri, fmaf( f1.y, rr, k01i[p]));
            k10r[p] = fmaf(f1.z, rr, fmaf(-f1.w, ri, k10r[p]));
            k10i[p] = fmaf(f1.z, ri, fmaf( f1.w, rr, k10i[p]));
            k11r[p] = fmaf(q1, rr, k11r[p]);
            k11i[p] = fmaf(q1, ri, k11i[p]);
        }
    }

    float2* __restrict__ row = at_out + (size_t)h * 2048;
#pragma unroll
    for (int p = 0; p < 4; ++p) {
        const int l = (half << 10) + (p << 8) + tid;
        const float dr = 1.0f + k11r[p], di = k11i[p];
        const float dinv = __builtin_amdgcn_rcpf(fmaf(dr, dr, di * di));
        const float pr_ = k01r[p] * k10r[p] - k01i[p] * k10i[p];
        const float pi_ = k01r[p] * k10i[p] + k01i[p] * k10r[p];
        const float qr = (pr_ * dr + pi_ * di) * dinv;
        const float qi = (pi_ * dr - pr_ * di) * dinv;
        const float sr = k00r[p] - qr, si = k00i[p] - qi;
        row[l] = make_float2(fmaf(-tt[p], si, sr), fmaf(tt[p], sr, si));
    }
}

// ---------------------------------------------------------------------------
// kf kernel (VERBATIM r7).
// ---------------------------------------------------------------------------
__global__ __launch_bounds__(256, 4)
void s4_kf_kernel(const float2* __restrict__ at_in, float2* __restrict__ Kf)
{
    __shared__ float2 bufA[LDSN];
    __shared__ float2 bufB[LDSN];

    const int h   = blockIdx.x;
    const int tid = threadIdx.x;
    const float2* __restrict__ at = at_in + (size_t)h * 2048;

    for (int q = 0; q < 8; ++q) {
        const int l = tid + (q << 8);
        bufA[PHYS(l)] = at[l];
    }

    float2* Kt = fft2048<1>(bufA, bufB);

    const float sc = 1.0f / 2048.0f;
    for (int n = tid; n < 1024; n += 256)
        bufB[PHYS(n)] = make_float2(Kt[PHYS(2 * n)].x * sc, Kt[PHYS(2 * n + 1)].x * sc);
    for (int n = 1024 + tid; n < 2048; n += 256)
        bufB[PHYS(n)] = make_float2(0.f, 0.f);

    float2* Z = fft2048<0>(bufB, bufA);

    float2* __restrict__ out = Kf + (size_t)h * 2049;
    for (int k = tid; k < 1024; k += 256) {
        const float2 Zk = Z[PHYS(k)];
        const float2 Zm = Z[PHYS((2048 - k) & 2047)];
        const float zer = 0.5f * (Zk.x + Zm.x), zei = 0.5f * (Zk.y - Zm.y);
        const float zdr = Zk.x - Zm.x,         zdi = Zk.y + Zm.y;
        const float zor = 0.5f * zdi,          zoi = -0.5f * zdr;
        float s, c;
        __sincosf(-PIf * (float)k * (1.0f / 2048.0f), &s, &c);
        const float txr = c * zor - s * zoi;
        const float txi = c * zoi + s * zor;
        out[k] = make_float2(zer + txr, zei + txi);
        if (k > 0) {
            out[2048 - k] = make_float2(zer - txr, txi - zei);
        } else {
            out[2048] = make_float2(Zk.x - Zk.y, 0.f);
        }
    }
    if (tid == 0) {
        const float2 z = Z[PHYS(1024)];
        out[1024] = make_float2(z.x, -z.y);
    }
}

// ---------------------------------------------------------------------------
// conv kernel — NEW: two rows (b0,h),(b0+1,h) packed as z = x0 + i*x1.
// Same-h rows share Kf, so Y = Z*Kf directly (no unpack/repack), and
// ifft(Y) = y0 + i*y1. One 4096-pt FFT pair per 2 rows, 512 threads.
// ---------------------------------------------------------------------------
__global__ __launch_bounds__(512, 8)
void s4_conv_kernel(const float* __restrict__ u, const float2* __restrict__ Kf,
                    const float* __restrict__ Dv, float* __restrict__ out)
{
    __shared__ float2 buf[LDSN4];

    const int bp  = blockIdx.x;           // 0..2047
    const int h   = bp & (HCH - 1);
    const int b0  = (bp >> 9) << 1;       // 0,2,4,6
    const int tid = threadIdx.x;

    const float* __restrict__ u0 = u + (size_t)b0 * LSEQ * HCH + h;
    const float* __restrict__ u1 = u0 + (size_t)LSEQ * HCH;

    // pack z[n] = x0[n] + i*x1[n] for n<2048, zero tail
#pragma unroll
    for (int m = 0; m < 4; ++m) {
        const int n = tid + (m << 9);
        buf[PHYS(n)]        = make_float2(u0[(size_t)n * HCH], u1[(size_t)n * HCH]);
        buf[PHYS(n + 2048)] = make_float2(0.f, 0.f);
    }

    radix8_ip4096<0, 0>(buf, tid);   // entry sync covers pack writes
    radix8_ip4096<0, 3>(buf, tid);
    radix8_ip4096<0, 6>(buf, tid);
    radix8_ip4096<0, 9>(buf, tid);

    // Y[k] = Z[k] * C[k];  C[k] = Kf[k] (k<=2048), conj(Kf[4096-k]) (k>2048).
    // Element-wise per-thread slots -> only an entry sync needed.
    const float2* __restrict__ kf = Kf + (size_t)h * 2049;
    __syncthreads();
#pragma unroll
    for (int m = 0; m < 8; ++m) {
        const int k = tid + (m << 9);
        float2 C;
        if (k <= 2048) {
            C = kf[k];
        } else {
            const float2 km = kf[4096 - k];
            C = make_float2(km.x, -km.y);
        }
        buf[PHYS(k)] = cmul(buf[PHYS(k)], C);
    }

    radix8_ip4096<1, 0>(buf, tid);   // entry sync covers multiply writes
    radix8_ip4096<1, 3>(buf, tid);
    radix8_ip4096<1, 6>(buf, tid);
    radix8_ip4096<1, 9>(buf, tid);

    __syncthreads();
    const float Dh = Dv[h];
    const float sc = 1.0f / 4096.0f;
    float* __restrict__ o0 = out + (size_t)b0 * LSEQ * HCH + h;
    float* __restrict__ o1 = o0 + (size_t)LSEQ * HCH;
#pragma unroll
    for (int m = 0; m < 4; ++m) {
        const int n = tid + (m << 9);
        const float2 w = buf[PHYS(n)];
        o0[(size_t)n * HCH] = fmaf(Dh, u0[(size_t)n * HCH], w.x * sc);
        o1[(size_t)n * HCH] = fmaf(Dh, u1[(size_t)n * HCH], w.y * sc);
    }
}

// ---------------------------------------------------------------------------
extern "C" void kernel_launch(void* const* d_in, const int* in_sizes, int n_in,
                              void* d_out, int out_size, void* d_ws, size_t ws_size,
                              hipStream_t stream)
{
    (void)in_sizes; (void)n_in; (void)out_size; (void)ws_size;
    const float* u  = (const float*)d_in[0];
    const float* Lr = (const float*)d_in[1];
    const float* Li = (const float*)d_in[2];
    const float* Pr = (const float*)d_in[3];
    const float* Pi = (const float*)d_in[4];
    const float* Br = (const float*)d_in[5];
    const float* Bi = (const float*)d_in[6];
    const float* Cr = (const float*)d_in[7];
    const float* Ci = (const float*)d_in[8];
    const float* ld = (const float*)d_in[9];
    const float* Dv = (const float*)d_in[10];
    float* out = (float*)d_out;

    // Kf in d_ws[0, 8.4MB)  (ws >= 8.4MB proven r5-r9).
    // at in d_out[0, 8MB)   (dead after kf; conv fully rewrites d_out).
    float2* Kf = (float2*)d_ws;
    float2* at = (float2*)d_out;

    hipLaunchKernelGGL(s4_cauchy_kernel, dim3(HCH * 2), dim3(256), 0, stream,
                       Lr, Li, Pr, Pi, Br, Bi, Cr, Ci, ld, at);
    hipLaunchKernelGGL(s4_kf_kernel, dim3(HCH), dim3(256), 0, stream, at, Kf);
    hipLaunchKernelGGL(s4_conv_kernel, dim3(NBATCH / 2 * HCH), dim3(512), 0, stream,
                       u, Kf, Dv, out);
}

// Round 11
// 303.289 us; speedup vs baseline: 1.0755x; 1.0755x over previous
//
#include <hip/hip_runtime.h>
#include <math.h>

#define LSEQ 2048
#define HCH  512
#define NST  64
#define NBATCH 8
#define PIf 3.14159265358979f

// Padded LDS layout: phys(i) = i + i/8 (verified r2)
#define PHYS(i) ((i) + ((i) >> 3))
#define LDSN 2304

__device__ __forceinline__ float2 cmul(float2 a, float2 b) {
    return make_float2(a.x * b.x - a.y * b.y, a.x * b.y + a.y * b.x);
}
__device__ __forceinline__ float2 cadd(float2 a, float2 b) { return make_float2(a.x + b.x, a.y + b.y); }
__device__ __forceinline__ float2 csub(float2 a, float2 b) { return make_float2(a.x - b.x, a.y - b.y); }
__device__ __forceinline__ float2 csq(float2 a) { return make_float2(a.x * a.x - a.y * a.y, 2.f * a.x * a.y); }
template<int INV>
__device__ __forceinline__ float2 rot90(float2 a) {
    return INV ? make_float2(-a.y, a.x) : make_float2(a.y, -a.x);
}

// ---------------------------------------------------------------------------
// Radix-8 Stockham pass, ping-pong (VERBATIM r2; kf kernel).
// ---------------------------------------------------------------------------
template<int INV, int STAGE>
__device__ __forceinline__ void radix8_pass(const float2* __restrict__ src,
                                            float2* __restrict__ dst, int tid)
{
    const int Ns  = 1 << STAGE;
    const int lam = tid & (Ns - 1);
    const int G   = ((tid >> STAGE) << (STAGE + 3)) + lam;

    float2 x0 = src[PHYS(tid)];
    float2 x1 = src[PHYS(tid + 256)];
    float2 x2 = src[PHYS(tid + 512)];
    float2 x3 = src[PHYS(tid + 768)];
    float2 x4 = src[PHYS(tid + 1024)];
    float2 x5 = src[PHYS(tid + 1280)];
    float2 x6 = src[PHYS(tid + 1536)];
    float2 x7 = src[PHYS(tid + 1792)];

    const float SGN = INV ? 1.f : -1.f;
    float sn, cs;
    __sincosf(SGN * (PIf / (float)(4 * Ns)) * (float)lam, &sn, &cs);
    const float2 T3 = make_float2(cs, sn);
    const float2 T2 = csq(T3);
    const float2 T1 = csq(T2);
    const float r2 = 0.70710678118f;
    const float2 U = cmul(T3, make_float2(r2, SGN * r2));

    float2 t;
    t = cmul(T1, x4); float2 a0 = cadd(x0, t), a4 = csub(x0, t);
    t = cmul(T1, x5); float2 a1 = cadd(x1, t), a5 = csub(x1, t);
    t = cmul(T1, x6); float2 a2 = cadd(x2, t), a6 = csub(x2, t);
    t = cmul(T1, x7); float2 a3 = cadd(x3, t), a7 = csub(x3, t);
    t = cmul(T2, a2);             float2 b0 = cadd(a0, t), b2 = csub(a0, t);
    t = cmul(T2, a3);             float2 b1 = cadd(a1, t), b3 = csub(a1, t);
    t = rot90<INV>(cmul(T2, a6)); float2 b4 = cadd(a4, t), b6 = csub(a4, t);
    t = rot90<INV>(cmul(T2, a7)); float2 b5 = cadd(a5, t), b7 = csub(a5, t);
    t = cmul(T3, b1);             dst[PHYS(G)]          = cadd(b0, t); dst[PHYS(G + 4 * Ns)] = csub(b0, t);
    t = rot90<INV>(cmul(T3, b3)); dst[PHYS(G + 2 * Ns)] = cadd(b2, t); dst[PHYS(G + 6 * Ns)] = csub(b2, t);
    t = cmul(U, b5);              dst[PHYS(G + Ns)]     = cadd(b4, t); dst[PHYS(G + 5 * Ns)] = csub(b4, t);
    t = rot90<INV>(cmul(U, b7));  dst[PHYS(G + 3 * Ns)] = cadd(b6, t); dst[PHYS(G + 7 * Ns)] = csub(b6, t);
}

template<int INV>
__device__ float2* fft2048(float2* bufA, float2* bufB)
{
    const int tid = threadIdx.x;
    __syncthreads();
    radix8_pass<INV, 0>(bufA, bufB, tid);
    __syncthreads();
    radix8_pass<INV, 3>(bufB, bufA, tid);
    __syncthreads();
    radix8_pass<INV, 6>(bufA, bufB, tid);
    __syncthreads();
    const float SGN = INV ? 1.f : -1.f;
#pragma unroll
    for (int q = 0; q < 2; ++q) {
        const int j = tid + (q << 8);
        float2 A  = bufB[PHYS(j)];
        float2 C  = bufB[PHYS(j + 512)];
        float2 B  = bufB[PHYS(j + 1024)];
        float2 Dd = bufB[PHYS(j + 1536)];
        float sn, cs;
        __sincosf(SGN * (PIf / 1024.f) * (float)j, &sn, &cs);
        const float2 v = make_float2(cs, sn);
        const float2 w = csq(v);
        float2 t = cmul(w, B);  float2 m1 = cadd(A, t), m2 = csub(A, t);
        t = cmul(w, Dd);        float2 m3 = cadd(C, t), m4 = csub(C, t);
        const float2 t3 = cmul(v, m3);
        const float2 t4 = rot90<INV>(cmul(v, m4));
        bufA[PHYS(j)]        = cadd(m1, t3);
        bufA[PHYS(j + 1024)] = csub(m1, t3);
        bufA[PHYS(j + 512)]  = cadd(m2, t4);
        bufA[PHYS(j + 1536)] = csub(m2, t4);
    }
    __syncthreads();
    return bufA;
}

// ---------------------------------------------------------------------------
// In-place FFT machinery (verified r8/r9; conv kernel).
// ---------------------------------------------------------------------------
template<int INV, int STAGE>
__device__ __forceinline__ void radix8_inplace(float2* __restrict__ buf, int tid)
{
    __syncthreads();
    float2 x0 = buf[PHYS(tid)];
    float2 x1 = buf[PHYS(tid + 256)];
    float2 x2 = buf[PHYS(tid + 512)];
    float2 x3 = buf[PHYS(tid + 768)];
    float2 x4 = buf[PHYS(tid + 1024)];
    float2 x5 = buf[PHYS(tid + 1280)];
    float2 x6 = buf[PHYS(tid + 1536)];
    float2 x7 = buf[PHYS(tid + 1792)];
    __syncthreads();

    const int Ns  = 1 << STAGE;
    const int lam = tid & (Ns - 1);
    const int G   = ((tid >> STAGE) << (STAGE + 3)) + lam;
    const float SGN = INV ? 1.f : -1.f;
    float sn, cs;
    __sincosf(SGN * (PIf / (float)(4 * Ns)) * (float)lam, &sn, &cs);
    const float2 T3 = make_float2(cs, sn);
    const float2 T2 = csq(T3);
    const float2 T1 = csq(T2);
    const float r2 = 0.70710678118f;
    const float2 U = cmul(T3, make_float2(r2, SGN * r2));
    float2 t;
    t = cmul(T1, x4); float2 a0 = cadd(x0, t), a4 = csub(x0, t);
    t = cmul(T1, x5); float2 a1 = cadd(x1, t), a5 = csub(x1, t);
    t = cmul(T1, x6); float2 a2 = cadd(x2, t), a6 = csub(x2, t);
    t = cmul(T1, x7); float2 a3 = cadd(x3, t), a7 = csub(x3, t);
    t = cmul(T2, a2);             float2 b0 = cadd(a0, t), b2 = csub(a0, t);
    t = cmul(T2, a3);             float2 b1 = cadd(a1, t), b3 = csub(a1, t);
    t = rot90<INV>(cmul(T2, a6)); float2 b4 = cadd(a4, t), b6 = csub(a4, t);
    t = rot90<INV>(cmul(T2, a7)); float2 b5 = cadd(a5, t), b7 = csub(a5, t);
    t = cmul(T3, b1);             buf[PHYS(G)]          = cadd(b0, t); buf[PHYS(G + 4 * Ns)] = csub(b0, t);
    t = rot90<INV>(cmul(T3, b3)); buf[PHYS(G + 2 * Ns)] = cadd(b2, t); buf[PHYS(G + 6 * Ns)] = csub(b2, t);
    t = cmul(U, b5);              buf[PHYS(G + Ns)]     = cadd(b4, t); buf[PHYS(G + 5 * Ns)] = csub(b4, t);
    t = rot90<INV>(cmul(U, b7));  buf[PHYS(G + 3 * Ns)] = cadd(b6, t); buf[PHYS(G + 7 * Ns)] = csub(b6, t);
}

template<int INV>
__device__ __forceinline__ void radix4_inplace(float2* __restrict__ buf, int tid)
{
    __syncthreads();
    const float SGN = INV ? 1.f : -1.f;
#pragma unroll
    for (int q = 0; q < 2; ++q) {
        const int j = tid + (q << 8);
        float2 A  = buf[PHYS(j)];
        float2 C  = buf[PHYS(j + 512)];
        float2 B  = buf[PHYS(j + 1024)];
        float2 Dd = buf[PHYS(j + 1536)];
        float sn, cs;
        __sincosf(SGN * (PIf / 1024.f) * (float)j, &sn, &cs);
        const float2 v = make_float2(cs, sn);
        const float2 w = csq(v);
        float2 t = cmul(w, B);  float2 m1 = cadd(A, t), m2 = csub(A, t);
        t = cmul(w, Dd);        float2 m3 = cadd(C, t), m4 = csub(C, t);
        const float2 t3 = cmul(v, m3);
        const float2 t4 = rot90<INV>(cmul(v, m4));
        buf[PHYS(j)]        = cadd(m1, t3);
        buf[PHYS(j + 1024)] = csub(m1, t3);
        buf[PHYS(j + 512)]  = cadd(m2, t4);
        buf[PHYS(j + 1536)] = csub(m2, t4);
    }
}

template<int INV>
__device__ __forceinline__ void fft2048_ip(float2* buf, int tid)
{
    radix8_inplace<INV, 0>(buf, tid);
    radix8_inplace<INV, 3>(buf, tid);
    radix8_inplace<INV, 6>(buf, tid);
    radix4_inplace<INV>(buf, tid);
}

// ---------------------------------------------------------------------------
// Cauchy (VERBATIM r7).
// ---------------------------------------------------------------------------
__global__ __launch_bounds__(256, 4)
void s4_cauchy_kernel(const float* __restrict__ Lr, const float* __restrict__ Li,
                      const float* __restrict__ Pr, const float* __restrict__ Pi,
                      const float* __restrict__ Br, const float* __restrict__ Bi,
                      const float* __restrict__ Cr, const float* __restrict__ Ci,
                      const float* __restrict__ log_dt, float2* __restrict__ at_out)
{
    __shared__ float4 F0[NST];
    __shared__ float4 F1[NST];
    __shared__ float  q1s[NST];

    const int h    = blockIdx.x >> 1;
    const int half = blockIdx.x & 1;
    const int tid  = threadIdx.x;

    if (tid < NST) {
        const float pr = Pr[tid], pi = Pi[tid], br = Br[tid], bi = Bi[tid];
        const float cr = Cr[h * NST + tid], ci = Ci[h * NST + tid];
        F0[tid]  = make_float4(Lr[tid], Li[tid], cr * br + ci * bi, cr * bi - ci * br);
        F1[tid]  = make_float4(cr * pr + ci * pi, cr * pi - ci * pr,
                               pr * br + pi * bi, pr * bi - pi * br);
        q1s[tid] = pr * pr + pi * pi;
    }
    __syncthreads();

    const float dt = expf(log_dt[h]);
    const float a  = 2.0f / dt;

    float tt[4], g[4];
#pragma unroll
    for (int p = 0; p < 4; ++p) {
        const int l = (half << 10) + (p << 8) + tid;
        tt[p] = tanf(PIf * (float)l * (1.0f / 2048.0f));
        g[p]  = a * tt[p];
    }

    float k00r[4], k00i[4], k01r[4], k01i[4];
    float k10r[4], k10i[4], k11r[4], k11i[4];
#pragma unroll
    for (int p = 0; p < 4; ++p) {
        k00r[p] = 0.f; k00i[p] = 0.f; k01r[p] = 0.f; k01i[p] = 0.f;
        k10r[p] = 0.f; k10i[p] = 0.f; k11r[p] = 0.f; k11i[p] = 0.f;
    }

#pragma unroll 2
    for (int n = 0; n < NST; ++n) {
        const float4 f0 = F0[n];
        const float4 f1 = F1[n];
        const float q1 = q1s[n];
        const float x  = -f0.x;
        const float x2 = x * x;
#pragma unroll
        for (int p = 0; p < 4; ++p) {
            const float y   = g[p] - f0.y;
            const float inv = __builtin_amdgcn_rcpf(fmaf(y, y, x2));
            const float rr  = x * inv;
            const float ri  = -y * inv;
            k00r[p] = fmaf(f0.z, rr, fmaf(-f0.w, ri, k00r[p]));
            k00i[p] = fmaf(f0.z, ri, fmaf( f0.w, rr, k00i[p]));
            k01r[p] = fmaf(f1.x, rr, fmaf(-f1.y, ri, k01r[p]));
            k01i[p] = fmaf(f1.x, ri, fmaf( f1.y, rr, k01i[p]));
            k10r[p] = fmaf(f1.z, rr, fmaf(-f1.w, ri, k10r[p]));
            k10i[p] = fmaf(f1.z, ri, fmaf( f1.w, rr, k10i[p]));
            k11r[p] = fmaf(q1, rr, k11r[p]);
            k11i[p] = fmaf(q1, ri, k11i[p]);
        }
    }

    float2* __restrict__ row = at_out + (size_t)h * 2048;
#pragma unroll
    for (int p = 0; p < 4; ++p) {
        const int l = (half << 10) + (p << 8) + tid;
        const float dr = 1.0f + k11r[p], di = k11i[p];
        const float dinv = __builtin_amdgcn_rcpf(fmaf(dr, dr, di * di));
        const float pr_ = k01r[p] * k10r[p] - k01i[p] * k10i[p];
        const float pi_ = k01r[p] * k10i[p] + k01i[p] * k10r[p];
        const float qr = (pr_ * dr + pi_ * di) * dinv;
        const float qi = (pi_ * dr - pr_ * di) * dinv;
        const float sr = k00r[p] - qr, si = k00i[p] - qi;
        row[l] = make_float2(fmaf(-tt[p], si, sr), fmaf(tt[p], sr, si));
    }
}

// ---------------------------------------------------------------------------
// kf kernel (VERBATIM r7).
// ---------------------------------------------------------------------------
__global__ __launch_bounds__(256, 4)
void s4_kf_kernel(const float2* __restrict__ at_in, float2* __restrict__ Kf)
{
    __shared__ float2 bufA[LDSN];
    __shared__ float2 bufB[LDSN];

    const int h   = blockIdx.x;
    const int tid = threadIdx.x;
    const float2* __restrict__ at = at_in + (size_t)h * 2048;

    for (int q = 0; q < 8; ++q) {
        const int l = tid + (q << 8);
        bufA[PHYS(l)] = at[l];
    }

    float2* Kt = fft2048<1>(bufA, bufB);

    const float sc = 1.0f / 2048.0f;
    for (int n = tid; n < 1024; n += 256)
        bufB[PHYS(n)] = make_float2(Kt[PHYS(2 * n)].x * sc, Kt[PHYS(2 * n + 1)].x * sc);
    for (int n = 1024 + tid; n < 2048; n += 256)
        bufB[PHYS(n)] = make_float2(0.f, 0.f);

    float2* Z = fft2048<0>(bufB, bufA);

    float2* __restrict__ out = Kf + (size_t)h * 2049;
    for (int k = tid; k < 1024; k += 256) {
        const float2 Zk = Z[PHYS(k)];
        const float2 Zm = Z[PHYS((2048 - k) & 2047)];
        const float zer = 0.5f * (Zk.x + Zm.x), zei = 0.5f * (Zk.y - Zm.y);
        const float zdr = Zk.x - Zm.x,         zdi = Zk.y + Zm.y;
        const float zor = 0.5f * zdi,          zoi = -0.5f * zdr;
        float s, c;
        __sincosf(-PIf * (float)k * (1.0f / 2048.0f), &s, &c);
        const float txr = c * zor - s * zoi;
        const float txi = c * zoi + s * zor;
        out[k] = make_float2(zer + txr, zei + txi);
        if (k > 0) {
            out[2048 - k] = make_float2(zer - txr, txi - zei);
        } else {
            out[2048] = make_float2(Zk.x - Zk.y, 0.f);
        }
    }
    if (tid == 0) {
        const float2 z = Z[PHYS(1024)];
        out[1024] = make_float2(z.x, -z.y);
    }
}

// ---------------------------------------------------------------------------
// conv kernel — r9-proven version (in-place FFT + fused mul/repack, strided
// IO, 4096 blocks x 256 thr, 18.4KB LDS). Dead fastpath branch removed;
// launch_bounds 6 -> 8 (the single perf knob this round).
// ---------------------------------------------------------------------------
__global__ __launch_bounds__(256, 8)
void s4_conv_kernel(const float* __restrict__ u, const float2* __restrict__ Kf,
                    const float* __restrict__ Dv, float* __restrict__ out)
{
    __shared__ float2 buf[LDSN];

    const int bh  = blockIdx.x;
    const int b   = bh >> 9;
    const int h   = bh & 511;
    const int tid = threadIdx.x;

    const float* __restrict__ ub = u + (size_t)b * LSEQ * HCH + h;

    // pack x: z[n] = x[2n] + i x[2n+1], zero tail
    for (int n = tid; n < 1024; n += 256)
        buf[PHYS(n)] = make_float2(ub[(size_t)(2 * n) * HCH],
                                   ub[(size_t)(2 * n + 1) * HCH]);
    for (int n = 1024 + tid; n < 2048; n += 256) buf[PHYS(n)] = make_float2(0.f, 0.f);

    fft2048_ip<0>(buf, tid);   // Z in buf

    const float2* __restrict__ kf = Kf + (size_t)h * 2049;

    // FUSED phase: read Z -> regs; sync; compute Yf=Xf*Kf and write W in place.
    __syncthreads();
    float2 Zk[4], Zm[4], Z1024v;
#pragma unroll
    for (int q = 0; q < 4; ++q) {
        const int k = tid + (q << 8);
        Zk[q] = buf[PHYS(k)];
        Zm[q] = buf[PHYS((2048 - k) & 2047)];
    }
    if (tid == 0) Z1024v = buf[PHYS(1024)];
    __syncthreads();

#pragma unroll
    for (int q = 0; q < 4; ++q) {
        const int k = tid + (q << 8);
        const float2 zk = Zk[q], zm = Zm[q];
        const float zer = 0.5f * (zk.x + zm.x), zei = 0.5f * (zk.y - zm.y);
        const float zdr = zk.x - zm.x,          zdi = zk.y + zm.y;
        const float zor = 0.5f * zdi,           zoi = -0.5f * zdr;
        float s, c;
        __sincosf(-PIf * (float)k * (1.0f / 2048.0f), &s, &c);   // s = -sin(pi k/2048)
        const float txr = c * zor - s * zoi;
        const float txi = c * zoi + s * zor;
        const float2 Xk = make_float2(zer + txr, zei + txi);     // Xf[k]
        float2 Yk = cmul(Xk, kf[k]);
        float2 Ym;
        if (k > 0) {
            const float2 Xm = make_float2(zer - txr, txi - zei); // Xf[2048-k]
            Ym = cmul(Xm, kf[2048 - k]);
        } else {
            const float x2048 = zk.x - zk.y;                     // Xf[2048] (real)
            const float2 k2 = kf[2048];
            Ym = make_float2(x2048 * k2.x, x2048 * k2.y);        // Y[2048]
        }
        // Repack: W[k] = E[k] + i O[k], with Y[k+2048] = conj(Y[2048-k]).
        const float yer = 0.5f * (Yk.x + Ym.x), yei = 0.5f * (Yk.y - Ym.y);
        const float ydr = Yk.x - Ym.x,          ydi = Yk.y + Ym.y;
        const float yor = 0.5f * (c * ydr + s * ydi);
        const float yoi = 0.5f * (c * ydi - s * ydr);
        buf[PHYS(k)] = make_float2(yer - yoi, yei + yor);
        if (k > 0)
            buf[PHYS(2048 - k)] = make_float2(yer + yoi, yor - yei);
    }
    if (tid == 0) {
        const float2 kk = kf[1024];
        const float2 y = make_float2(Z1024v.x * kk.x + Z1024v.y * kk.y,
                                     Z1024v.x * kk.y - Z1024v.y * kk.x);
        buf[PHYS(1024)] = make_float2(y.x, -y.y);
    }

    fft2048_ip<1>(buf, tid);   // entry sync covers fused-phase writes; w in buf

    __syncthreads();
    const float Dh = Dv[h];
    const float sc = 1.0f / 2048.0f;
    float* __restrict__ ob = out + (size_t)b * LSEQ * HCH + h;
    for (int n = tid; n < 1024; n += 256) {
        const float2 wv = buf[PHYS(n)];
        ob[(size_t)(2 * n) * HCH]     = wv.x * sc + Dh * ub[(size_t)(2 * n) * HCH];
        ob[(size_t)(2 * n + 1) * HCH] = wv.y * sc + Dh * ub[(size_t)(2 * n + 1) * HCH];
    }
}

// ---------------------------------------------------------------------------
extern "C" void kernel_launch(void* const* d_in, const int* in_sizes, int n_in,
                              void* d_out, int out_size, void* d_ws, size_t ws_size,
                              hipStream_t stream)
{
    (void)in_sizes; (void)n_in; (void)out_size; (void)ws_size;
    const float* u  = (const float*)d_in[0];
    const float* Lr = (const float*)d_in[1];
    const float* Li = (const float*)d_in[2];
    const float* Pr = (const float*)d_in[3];
    const float* Pi = (const float*)d_in[4];
    const float* Br = (const float*)d_in[5];
    const float* Bi = (const float*)d_in[6];
    const float* Cr = (const float*)d_in[7];
    const float* Ci = (const float*)d_in[8];
    const float* ld = (const float*)d_in[9];
    const float* Dv = (const float*)d_in[10];
    float* out = (float*)d_out;

    // Kf in d_ws[0, 8.4MB)  (ws >= 8.4MB proven r5-r10).
    // at in d_out[0, 8MB)   (dead after kf; conv fully rewrites d_out).
    float2* Kf = (float2*)d_ws;
    float2* at = (float2*)d_out;

    hipLaunchKernelGGL(s4_cauchy_kernel, dim3(HCH * 2), dim3(256), 0, stream,
                       Lr, Li, Pr, Pi, Br, Bi, Cr, Ci, ld, at);
    hipLaunchKernelGGL(s4_kf_kernel, dim3(HCH), dim3(256), 0, stream, at, Kf);
    hipLaunchKernelGGL(s4_conv_kernel, dim3(NBATCH * HCH), dim3(256), 0, stream,
                       u, Kf, Dv, out);
}

// Round 12
// 110.031 us; speedup vs baseline: 2.9646x; 2.7564x over previous
//
#include <hip/hip_runtime.h>
#include <math.h>

#define LSEQ 2048
#define HCH  512
#define NST  64
#define NBATCH 8
#define PIf 3.14159265358979f

// Padded LDS layout: phys(i) = i + i/8 (verified r2)
#define PHYS(i) ((i) + ((i) >> 3))
#define LDSN 2304

__device__ __forceinline__ float2 cmul(float2 a, float2 b) {
    return make_float2(a.x * b.x - a.y * b.y, a.x * b.y + a.y * b.x);
}
__device__ __forceinline__ float2 cadd(float2 a, float2 b) { return make_float2(a.x + b.x, a.y + b.y); }
__device__ __forceinline__ float2 csub(float2 a, float2 b) { return make_float2(a.x - b.x, a.y - b.y); }
__device__ __forceinline__ float2 csq(float2 a) { return make_float2(a.x * a.x - a.y * a.y, 2.f * a.x * a.y); }
template<int INV>
__device__ __forceinline__ float2 rot90(float2 a) {
    return INV ? make_float2(-a.y, a.x) : make_float2(a.y, -a.x);
}

// ---------------------------------------------------------------------------
// Radix-8 Stockham pass, ping-pong (VERBATIM r2). Used by kf kernel.
// ---------------------------------------------------------------------------
template<int INV, int STAGE>
__device__ __forceinline__ void radix8_pass(const float2* __restrict__ src,
                                            float2* __restrict__ dst, int tid)
{
    const int Ns  = 1 << STAGE;
    const int lam = tid & (Ns - 1);
    const int G   = ((tid >> STAGE) << (STAGE + 3)) + lam;

    float2 x0 = src[PHYS(tid)];
    float2 x1 = src[PHYS(tid + 256)];
    float2 x2 = src[PHYS(tid + 512)];
    float2 x3 = src[PHYS(tid + 768)];
    float2 x4 = src[PHYS(tid + 1024)];
    float2 x5 = src[PHYS(tid + 1280)];
    float2 x6 = src[PHYS(tid + 1536)];
    float2 x7 = src[PHYS(tid + 1792)];

    const float SGN = INV ? 1.f : -1.f;
    float sn, cs;
    __sincosf(SGN * (PIf / (float)(4 * Ns)) * (float)lam, &sn, &cs);
    const float2 T3 = make_float2(cs, sn);
    const float2 T2 = csq(T3);
    const float2 T1 = csq(T2);
    const float r2 = 0.70710678118f;
    const float2 U = cmul(T3, make_float2(r2, SGN * r2));

    float2 t;
    t = cmul(T1, x4); float2 a0 = cadd(x0, t), a4 = csub(x0, t);
    t = cmul(T1, x5); float2 a1 = cadd(x1, t), a5 = csub(x1, t);
    t = cmul(T1, x6); float2 a2 = cadd(x2, t), a6 = csub(x2, t);
    t = cmul(T1, x7); float2 a3 = cadd(x3, t), a7 = csub(x3, t);
    t = cmul(T2, a2);             float2 b0 = cadd(a0, t), b2 = csub(a0, t);
    t = cmul(T2, a3);             float2 b1 = cadd(a1, t), b3 = csub(a1, t);
    t = rot90<INV>(cmul(T2, a6)); float2 b4 = cadd(a4, t), b6 = csub(a4, t);
    t = rot90<INV>(cmul(T2, a7)); float2 b5 = cadd(a5, t), b7 = csub(a5, t);
    t = cmul(T3, b1);             dst[PHYS(G)]          = cadd(b0, t); dst[PHYS(G + 4 * Ns)] = csub(b0, t);
    t = rot90<INV>(cmul(T3, b3)); dst[PHYS(G + 2 * Ns)] = cadd(b2, t); dst[PHYS(G + 6 * Ns)] = csub(b2, t);
    t = cmul(U, b5);              dst[PHYS(G + Ns)]     = cadd(b4, t); dst[PHYS(G + 5 * Ns)] = csub(b4, t);
    t = rot90<INV>(cmul(U, b7));  dst[PHYS(G + 3 * Ns)] = cadd(b6, t); dst[PHYS(G + 7 * Ns)] = csub(b6, t);
}

template<int INV>
__device__ float2* fft2048(float2* bufA, float2* bufB)
{
    const int tid = threadIdx.x;
    __syncthreads();
    radix8_pass<INV, 0>(bufA, bufB, tid);
    __syncthreads();
    radix8_pass<INV, 3>(bufB, bufA, tid);
    __syncthreads();
    radix8_pass<INV, 6>(bufA, bufB, tid);
    __syncthreads();
    const float SGN = INV ? 1.f : -1.f;
#pragma unroll
    for (int q = 0; q < 2; ++q) {
        const int j = tid + (q << 8);
        float2 A  = bufB[PHYS(j)];
        float2 C  = bufB[PHYS(j + 512)];
        float2 B  = bufB[PHYS(j + 1024)];
        float2 Dd = bufB[PHYS(j + 1536)];
        float sn, cs;
        __sincosf(SGN * (PIf / 1024.f) * (float)j, &sn, &cs);
        const float2 v = make_float2(cs, sn);
        const float2 w = csq(v);
        float2 t = cmul(w, B);  float2 m1 = cadd(A, t), m2 = csub(A, t);
        t = cmul(w, Dd);        float2 m3 = cadd(C, t), m4 = csub(C, t);
        const float2 t3 = cmul(v, m3);
        const float2 t4 = rot90<INV>(cmul(v, m4));
        bufA[PHYS(j)]        = cadd(m1, t3);
        bufA[PHYS(j + 1024)] = csub(m1, t3);
        bufA[PHYS(j + 512)]  = cadd(m2, t4);
        bufA[PHYS(j + 1536)] = csub(m2, t4);
    }
    __syncthreads();
    return bufA;
}

// ---------------------------------------------------------------------------
// In-place FFT machinery (verified r8).
// ---------------------------------------------------------------------------
template<int INV, int STAGE>
__device__ __forceinline__ void radix8_inplace(float2* __restrict__ buf, int tid)
{
    __syncthreads();
    float2 x0 = buf[PHYS(tid)];
    float2 x1 = buf[PHYS(tid + 256)];
    float2 x2 = buf[PHYS(tid + 512)];
    float2 x3 = buf[PHYS(tid + 768)];
    float2 x4 = buf[PHYS(tid + 1024)];
    float2 x5 = buf[PHYS(tid + 1280)];
    float2 x6 = buf[PHYS(tid + 1536)];
    float2 x7 = buf[PHYS(tid + 1792)];
    __syncthreads();

    const int Ns  = 1 << STAGE;
    const int lam = tid & (Ns - 1);
    const int G   = ((tid >> STAGE) << (STAGE + 3)) + lam;
    const float SGN = INV ? 1.f : -1.f;
    float sn, cs;
    __sincosf(SGN * (PIf / (float)(4 * Ns)) * (float)lam, &sn, &cs);
    const float2 T3 = make_float2(cs, sn);
    const float2 T2 = csq(T3);
    const float2 T1 = csq(T2);
    const float r2 = 0.70710678118f;
    const float2 U = cmul(T3, make_float2(r2, SGN * r2));
    float2 t;
    t = cmul(T1, x4); float2 a0 = cadd(x0, t), a4 = csub(x0, t);
    t = cmul(T1, x5); float2 a1 = cadd(x1, t), a5 = csub(x1, t);
    t = cmul(T1, x6); float2 a2 = cadd(x2, t), a6 = csub(x2, t);
    t = cmul(T1, x7); float2 a3 = cadd(x3, t), a7 = csub(x3, t);
    t = cmul(T2, a2);             float2 b0 = cadd(a0, t), b2 = csub(a0, t);
    t = cmul(T2, a3);             float2 b1 = cadd(a1, t), b3 = csub(a1, t);
    t = rot90<INV>(cmul(T2, a6)); float2 b4 = cadd(a4, t), b6 = csub(a4, t);
    t = rot90<INV>(cmul(T2, a7)); float2 b5 = cadd(a5, t), b7 = csub(a5, t);
    t = cmul(T3, b1);             buf[PHYS(G)]          = cadd(b0, t); buf[PHYS(G + 4 * Ns)] = csub(b0, t);
    t = rot90<INV>(cmul(T3, b3)); buf[PHYS(G + 2 * Ns)] = cadd(b2, t); buf[PHYS(G + 6 * Ns)] = csub(b2, t);
    t = cmul(U, b5);              buf[PHYS(G + Ns)]     = cadd(b4, t); buf[PHYS(G + 5 * Ns)] = csub(b4, t);
    t = rot90<INV>(cmul(U, b7));  buf[PHYS(G + 3 * Ns)] = cadd(b6, t); buf[PHYS(G + 7 * Ns)] = csub(b6, t);
}

template<int INV>
__device__ __forceinline__ void radix4_inplace(float2* __restrict__ buf, int tid)
{
    __syncthreads();
    const float SGN = INV ? 1.f : -1.f;
#pragma unroll
    for (int q = 0; q < 2; ++q) {
        const int j = tid + (q << 8);
        float2 A  = buf[PHYS(j)];
        float2 C  = buf[PHYS(j + 512)];
        float2 B  = buf[PHYS(j + 1024)];
        float2 Dd = buf[PHYS(j + 1536)];
        float sn, cs;
        __sincosf(SGN * (PIf / 1024.f) * (float)j, &sn, &cs);
        const float2 v = make_float2(cs, sn);
        const float2 w = csq(v);
        float2 t = cmul(w, B);  float2 m1 = cadd(A, t), m2 = csub(A, t);
        t = cmul(w, Dd);        float2 m3 = cadd(C, t), m4 = csub(C, t);
        const float2 t3 = cmul(v, m3);
        const float2 t4 = rot90<INV>(cmul(v, m4));
        buf[PHYS(j)]        = cadd(m1, t3);
        buf[PHYS(j + 1024)] = csub(m1, t3);
        buf[PHYS(j + 512)]  = cadd(m2, t4);
        buf[PHYS(j + 1536)] = csub(m2, t4);
    }
}

template<int INV>
__device__ __forceinline__ void fft2048_ip(float2* buf, int tid)
{
    radix8_inplace<INV, 0>(buf, tid);
    radix8_inplace<INV, 3>(buf, tid);
    radix8_inplace<INV, 6>(buf, tid);
    radix4_inplace<INV>(buf, tid);
}

// ---------------------------------------------------------------------------
// Cauchy (VERBATIM r7).
// ---------------------------------------------------------------------------
__global__ __launch_bounds__(256, 4)
void s4_cauchy_kernel(const float* __restrict__ Lr, const float* __restrict__ Li,
                      const float* __restrict__ Pr, const float* __restrict__ Pi,
                      const float* __restrict__ Br, const float* __restrict__ Bi,
                      const float* __restrict__ Cr, const float* __restrict__ Ci,
                      const float* __restrict__ log_dt, float2* __restrict__ at_out)
{
    __shared__ float4 F0[NST];
    __shared__ float4 F1[NST];
    __shared__ float  q1s[NST];

    const int h    = blockIdx.x >> 1;
    const int half = blockIdx.x & 1;
    const int tid  = threadIdx.x;

    if (tid < NST) {
        const float pr = Pr[tid], pi = Pi[tid], br = Br[tid], bi = Bi[tid];
        const float cr = Cr[h * NST + tid], ci = Ci[h * NST + tid];
        F0[tid]  = make_float4(Lr[tid], Li[tid], cr * br + ci * bi, cr * bi - ci * br);
        F1[tid]  = make_float4(cr * pr + ci * pi, cr * pi - ci * pr,
                               pr * br + pi * bi, pr * bi - pi * br);
        q1s[tid] = pr * pr + pi * pi;
    }
    __syncthreads();

    const float dt = expf(log_dt[h]);
    const float a  = 2.0f / dt;

    float tt[4], g[4];
#pragma unroll
    for (int p = 0; p < 4; ++p) {
        const int l = (half << 10) + (p << 8) + tid;
        tt[p] = tanf(PIf * (float)l * (1.0f / 2048.0f));
        g[p]  = a * tt[p];
    }

    float k00r[4], k00i[4], k01r[4], k01i[4];
    float k10r[4], k10i[4], k11r[4], k11i[4];
#pragma unroll
    for (int p = 0; p < 4; ++p) {
        k00r[p] = 0.f; k00i[p] = 0.f; k01r[p] = 0.f; k01i[p] = 0.f;
        k10r[p] = 0.f; k10i[p] = 0.f; k11r[p] = 0.f; k11i[p] = 0.f;
    }

#pragma unroll 2
    for (int n = 0; n < NST; ++n) {
        const float4 f0 = F0[n];
        const float4 f1 = F1[n];
        const float q1 = q1s[n];
        const float x  = -f0.x;
        const float x2 = x * x;
#pragma unroll
        for (int p = 0; p < 4; ++p) {
            const float y   = g[p] - f0.y;
            const float inv = __builtin_amdgcn_rcpf(fmaf(y, y, x2));
            const float rr  = x * inv;
            const float ri  = -y * inv;
            k00r[p] = fmaf(f0.z, rr, fmaf(-f0.w, ri, k00r[p]));
            k00i[p] = fmaf(f0.z, ri, fmaf( f0.w, rr, k00i[p]));
            k01r[p] = fmaf(f1.x, rr, fmaf(-f1.y, ri, k01r[p]));
            k01i[p] = fmaf(f1.x, ri, fmaf( f1.y, rr, k01i[p]));
            k10r[p] = fmaf(f1.z, rr, fmaf(-f1.w, ri, k10r[p]));
            k10i[p] = fmaf(f1.z, ri, fmaf( f1.w, rr, k10i[p]));
            k11r[p] = fmaf(q1, rr, k11r[p]);
            k11i[p] = fmaf(q1, ri, k11i[p]);
        }
    }

    float2* __restrict__ row = at_out + (size_t)h * 2048;
#pragma unroll
    for (int p = 0; p < 4; ++p) {
        const int l = (half << 10) + (p << 8) + tid;
        const float dr = 1.0f + k11r[p], di = k11i[p];
        const float dinv = __builtin_amdgcn_rcpf(fmaf(dr, dr, di * di));
        const float pr_ = k01r[p] * k10r[p] - k01i[p] * k10i[p];
        const float pi_ = k01r[p] * k10i[p] + k01i[p] * k10r[p];
        const float qr = (pr_ * dr + pi_ * di) * dinv;
        const float qi = (pi_ * dr - pr_ * di) * dinv;
        const float sr = k00r[p] - qr, si = k00i[p] - qi;
        row[l] = make_float2(fmaf(-tt[p], si, sr), fmaf(tt[p], sr, si));
    }
}

// ---------------------------------------------------------------------------
// kf kernel (VERBATIM r7).
// ---------------------------------------------------------------------------
__global__ __launch_bounds__(256, 4)
void s4_kf_kernel(const float2* __restrict__ at_in, float2* __restrict__ Kf)
{
    __shared__ float2 bufA[LDSN];
    __shared__ float2 bufB[LDSN];

    const int h   = blockIdx.x;
    const int tid = threadIdx.x;
    const float2* __restrict__ at = at_in + (size_t)h * 2048;

    for (int q = 0; q < 8; ++q) {
        const int l = tid + (q << 8);
        bufA[PHYS(l)] = at[l];
    }

    float2* Kt = fft2048<1>(bufA, bufB);

    const float sc = 1.0f / 2048.0f;
    for (int n = tid; n < 1024; n += 256)
        bufB[PHYS(n)] = make_float2(Kt[PHYS(2 * n)].x * sc, Kt[PHYS(2 * n + 1)].x * sc);
    for (int n = 1024 + tid; n < 2048; n += 256)
        bufB[PHYS(n)] = make_float2(0.f, 0.f);

    float2* Z = fft2048<0>(bufB, bufA);

    float2* __restrict__ out = Kf + (size_t)h * 2049;
    for (int k = tid; k < 1024; k += 256) {
        const float2 Zk = Z[PHYS(k)];
        const float2 Zm = Z[PHYS((2048 - k) & 2047)];
        const float zer = 0.5f * (Zk.x + Zm.x), zei = 0.5f * (Zk.y - Zm.y);
        const float zdr = Zk.x - Zm.x,         zdi = Zk.y + Zm.y;
        const float zor = 0.5f * zdi,          zoi = -0.5f * zdr;
        float s, c;
        __sincosf(-PIf * (float)k * (1.0f / 2048.0f), &s, &c);
        const float txr = c * zor - s * zoi;
        const float txi = c * zoi + s * zor;
        out[k] = make_float2(zer + txr, zei + txi);
        if (k > 0) {
            out[2048 - k] = make_float2(zer - txr, txi - zei);
        } else {
            out[2048] = make_float2(Zk.x - Zk.y, 0.f);
        }
    }
    if (tid == 0) {
        const float2 z = Z[PHYS(1024)];
        out[1024] = make_float2(z.x, -z.y);
    }
}

// ---------------------------------------------------------------------------
// conv kernel (VERBATIM r9 — the empirically-good config: launch_bounds(256,6),
// in-place FFT + fused mul/repack, ~47% occupancy keeps the strided-IO line
// working set inside L3; r10/r11 showed higher occupancy explodes HBM traffic).
// ---------------------------------------------------------------------------
__global__ __launch_bounds__(256, 6)
void s4_conv_kernel(const float* __restrict__ u, float* ws_rows,
                    const float2* __restrict__ Kf, const float* __restrict__ Dv,
                    float* __restrict__ out, int fastpath)
{
    __shared__ float2 buf[LDSN];

    const int bh  = blockIdx.x;
    const int b   = bh >> 9;
    const int h   = bh & 511;
    const int tid = threadIdx.x;

    // pack x: z[n] = x[2n] + i x[2n+1], zero tail
    if (fastpath) {
        const float2* rowv = (const float2*)(ws_rows + (size_t)bh * LSEQ);
        for (int n = tid; n < 1024; n += 256) buf[PHYS(n)] = rowv[n];
    } else {
        const float* ub = u + (size_t)b * LSEQ * HCH + h;
        for (int n = tid; n < 1024; n += 256)
            buf[PHYS(n)] = make_float2(ub[(size_t)(2 * n) * HCH],
                                       ub[(size_t)(2 * n + 1) * HCH]);
    }
    for (int n = 1024 + tid; n < 2048; n += 256) buf[PHYS(n)] = make_float2(0.f, 0.f);

    fft2048_ip<0>(buf, tid);   // Z in buf

    const float2* __restrict__ kf = Kf + (size_t)h * 2049;

    // FUSED phase: read Z -> regs; sync; compute Yf=Xf*Kf and write W in place.
    __syncthreads();
    float2 Zk[4], Zm[4], Z1024v;
#pragma unroll
    for (int q = 0; q < 4; ++q) {
        const int k = tid + (q << 8);
        Zk[q] = buf[PHYS(k)];
        Zm[q] = buf[PHYS((2048 - k) & 2047)];
    }
    if (tid == 0) Z1024v = buf[PHYS(1024)];
    __syncthreads();

#pragma unroll
    for (int q = 0; q < 4; ++q) {
        const int k = tid + (q << 8);
        const float2 zk = Zk[q], zm = Zm[q];
        const float zer = 0.5f * (zk.x + zm.x), zei = 0.5f * (zk.y - zm.y);
        const float zdr = zk.x - zm.x,          zdi = zk.y + zm.y;
        const float zor = 0.5f * zdi,           zoi = -0.5f * zdr;
        float s, c;
        __sincosf(-PIf * (float)k * (1.0f / 2048.0f), &s, &c);   // s = -sin(pi k/2048)
        const float txr = c * zor - s * zoi;
        const float txi = c * zoi + s * zor;
        const float2 Xk = make_float2(zer + txr, zei + txi);     // Xf[k]
        float2 Yk = cmul(Xk, kf[k]);
        float2 Ym;
        if (k > 0) {
            const float2 Xm = make_float2(zer - txr, txi - zei); // Xf[2048-k]
            Ym = cmul(Xm, kf[2048 - k]);
        } else {
            const float x2048 = zk.x - zk.y;                     // Xf[2048] (real)
            const float2 k2 = kf[2048];
            Ym = make_float2(x2048 * k2.x, x2048 * k2.y);        // Y[2048]
        }
        // Repack: W[k] = E[k] + i O[k], with Y[k+2048] = conj(Y[2048-k]).
        const float yer = 0.5f * (Yk.x + Ym.x), yei = 0.5f * (Yk.y - Ym.y);
        const float ydr = Yk.x - Ym.x,          ydi = Yk.y + Ym.y;
        const float yor = 0.5f * (c * ydr + s * ydi);
        const float yoi = 0.5f * (c * ydi - s * ydr);
        buf[PHYS(k)] = make_float2(yer - yoi, yei + yor);
        if (k > 0)
            buf[PHYS(2048 - k)] = make_float2(yer + yoi, yor - yei);
    }
    if (tid == 0) {
        const float2 kk = kf[1024];
        const float2 y = make_float2(Z1024v.x * kk.x + Z1024v.y * kk.y,
                                     Z1024v.x * kk.y - Z1024v.y * kk.x);
        buf[PHYS(1024)] = make_float2(y.x, -y.y);
    }

    fft2048_ip<1>(buf, tid);   // entry sync covers fused-phase writes; w in buf

    __syncthreads();
    const float Dh = Dv[h];
    const float sc = 1.0f / 2048.0f;
    if (fastpath) {
        float2* rowv = (float2*)(ws_rows + (size_t)bh * LSEQ);
        for (int n = tid; n < 1024; n += 256) {
            const float2 wv = buf[PHYS(n)];
            const float2 xv = rowv[n];
            rowv[n] = make_float2(wv.x * sc + Dh * xv.x,
                                  wv.y * sc + Dh * xv.y);
        }
    } else {
        const float* ub = u + (size_t)b * LSEQ * HCH + h;
        float* ob = out + (size_t)b * LSEQ * HCH + h;
        for (int n = tid; n < 1024; n += 256) {
            const float2 wv = buf[PHYS(n)];
            ob[(size_t)(2 * n) * HCH]     = wv.x * sc + Dh * ub[(size_t)(2 * n) * HCH];
            ob[(size_t)(2 * n + 1) * HCH] = wv.y * sc + Dh * ub[(size_t)(2 * n + 1) * HCH];
        }
    }
}

// ---------------------------------------------------------------------------
// transpose (VERBATIM r7)
// ---------------------------------------------------------------------------
__global__ __launch_bounds__(256)
void transpose_kernel(const float* __restrict__ in, float* __restrict__ out,
                      int rows, int cols)
{
    __shared__ float tile[32][33];
    const int b  = blockIdx.z;
    const int r0 = blockIdx.y << 5;
    const int c0 = blockIdx.x << 5;
    const size_t base = (size_t)b * rows * cols;
    const int tx = threadIdx.x & 31;
    const int ty = threadIdx.x >> 5;
#pragma unroll
    for (int i = 0; i < 32; i += 8)
        tile[ty + i][tx] = in[base + (size_t)(r0 + ty + i) * cols + (c0 + tx)];
    __syncthreads();
#pragma unroll
    for (int i = 0; i < 32; i += 8)
        out[base + (size_t)(c0 + ty + i) * rows + (r0 + tx)] = tile[tx][ty + i];
}

// ---------------------------------------------------------------------------
extern "C" void kernel_launch(void* const* d_in, const int* in_sizes, int n_in,
                              void* d_out, int out_size, void* d_ws, size_t ws_size,
                              hipStream_t stream)
{
    (void)in_sizes; (void)n_in; (void)out_size;
    const float* u  = (const float*)d_in[0];
    const float* Lr = (const float*)d_in[1];
    const float* Li = (const float*)d_in[2];
    const float* Pr = (const float*)d_in[3];
    const float* Pi = (const float*)d_in[4];
    const float* Br = (const float*)d_in[5];
    const float* Bi = (const float*)d_in[6];
    const float* Cr = (const float*)d_in[7];
    const float* Ci = (const float*)d_in[8];
    const float* ld = (const float*)d_in[9];
    const float* Dv = (const float*)d_in[10];
    float* out = (float*)d_out;

    const size_t UT_BYTES = (size_t)NBATCH * HCH * LSEQ * sizeof(float);   // 32 MB
    const size_t KF_BYTES = (size_t)HCH * 2049 * sizeof(float2);           // 8.4 MB
    const int fast = (ws_size >= UT_BYTES + KF_BYTES) ? 1 : 0;

    float*  ut;
    float2* Kf;
    if (fast) { ut = (float*)d_ws; Kf = (float2*)((char*)d_ws + UT_BYTES); }
    else      { ut = (float*)d_ws; Kf = (float2*)d_ws; }

    // at staged in d_out[0, 8MB) — r5-verified placement.
    float2* at = (float2*)d_out;

    hipLaunchKernelGGL(s4_cauchy_kernel, dim3(HCH * 2), dim3(256), 0, stream,
                       Lr, Li, Pr, Pi, Br, Bi, Cr, Ci, ld, at);
    hipLaunchKernelGGL(s4_kf_kernel, dim3(HCH), dim3(256), 0, stream, at, Kf);
    if (fast) {
        hipLaunchKernelGGL(transpose_kernel, dim3(HCH / 32, LSEQ / 32, NBATCH),
                           dim3(256), 0, stream, u, ut, LSEQ, HCH);
    }
    hipLaunchKernelGGL(s4_conv_kernel, dim3(NBATCH * HCH), dim3(256), 0, stream,
                       u, fast ? ut : nullptr, Kf, Dv, out, fast);
    if (fast) {
        hipLaunchKernelGGL(transpose_kernel, dim3(LSEQ / 32, HCH / 32, NBATCH),
                           dim3(256), 0, stream, ut, out, HCH, LSEQ);
    }
}